// Round 1
// 381.383 us; speedup vs baseline: 1.0100x; 1.0100x over previous
//
#include <hip/hip_runtime.h>
#include <hip/hip_bf16.h>
#include <stdint.h>

typedef __bf16 bf16_t;
typedef __bf16 bf16x4 __attribute__((ext_vector_type(4)));
typedef __bf16 bf16x8 __attribute__((ext_vector_type(8)));
typedef float floatx4 __attribute__((ext_vector_type(4)));

#define B_ 32
#define HP 58
#define WP 66

// ws layout (bytes)
#define XPAD_OFF   0u
#define WAGG_OFF   62717952u     // 32*58*66*256*2
#define POOLED_OFF 100466688u    // + 32*9*256*256*2
#define ATTN_OFF   100499456u
#define BIASAGG_OFF 100499968u

__device__ __forceinline__ void async_copy16(const void* gsrc, void* ldst) {
  __builtin_amdgcn_global_load_lds(
      (const __attribute__((address_space(1))) unsigned int*)gsrc,
      (__attribute__((address_space(3))) unsigned int*)ldst, 16, 0, 0);
}

// ---------------- kernel 1: pad + convert + GAP partial sums ----------------
// vectorized: wave covers all 256 c as float4; bf16x4 stores; LDS reduce then 4 atomics/lane
__global__ __launch_bounds__(256)
void pad_pool(const float* __restrict__ x, bf16_t* __restrict__ xpad,
              float* __restrict__ pooled) {
  const int hp = blockIdx.x;   // 0..57
  const int b  = blockIdx.y;
  const int t  = threadIdx.x;
  const int c4 = (t & 63) << 2;   // 0..252 (float4 channel group)
  const int wq = t >> 6;          // 0..3
  const int h  = hp - 1;
  const bool hvalid = (h >= 0) && (h < 56);
  bf16_t* dst = xpad + ((size_t)(b * 58 + hp)) * (66 * 256);
  const float* srcrow = x + ((size_t)(b * 56 + (hvalid ? h : 0))) * (56 * 256);
  floatx4 sum = {0.f, 0.f, 0.f, 0.f};
  for (int wp = wq; wp < 66; wp += 4) {
    const int w = wp - 1;
    floatx4 v = {0.f, 0.f, 0.f, 0.f};
    if (hvalid && (unsigned)w < 56u) {
      v = *(const floatx4*)(srcrow + w * 256 + c4);
      sum += v;
    }
    bf16x4 r;
#pragma unroll
    for (int j = 0; j < 4; ++j) r[j] = (bf16_t)v[j];
    *(bf16x4*)(dst + wp * 256 + c4) = r;
  }
  __shared__ floatx4 red[4][64];
  red[wq][t & 63] = sum;
  __syncthreads();
  if (hvalid && t < 64) {
    floatx4 s = red[0][t] + red[1][t] + red[2][t] + red[3][t];
#pragma unroll
    for (int j = 0; j < 4; ++j) atomicAdd(&pooled[b * 256 + t * 4 + j], s[j]);
  }
}

// ---------------- kernel 2: router MLP + softmax + bias agg ----------------
// w1 staged in LDS; 4-way ILP accumulators in the hidden-layer dot products.
__global__ __launch_bounds__(256)
void router(const float* __restrict__ pooled, const float* __restrict__ w1,
            const float* __restrict__ b1, const float* __restrict__ w2,
            const float* __restrict__ b2, const float* __restrict__ biases,
            float* __restrict__ attn, float* __restrict__ biasagg) {
  __shared__ float ps[8192];
  __shared__ float w1s[16384];
  __shared__ float hs[2048];
  __shared__ float lg[128];
  __shared__ float at[128];
  const int t = threadIdx.x;
  for (int i = t; i < 8192; i += 256) ps[i] = pooled[i] * (1.0f / 3136.0f);
  for (int i = t; i < 4096; i += 256)
    *(floatx4*)&w1s[i * 4] = *(const floatx4*)&w1[i * 4];
  __syncthreads();
  for (int task = t; task < 2048; task += 256) {
    const int b = task >> 6, j = task & 63;
    const float* pb = ps + b * 256;
    float s0 = 0.f, s1 = 0.f, s2 = 0.f, s3 = 0.f;
#pragma unroll 4
    for (int c = 0; c < 256; c += 4) {
      s0 += pb[c]     * w1s[c * 64 + j];
      s1 += pb[c + 1] * w1s[(c + 1) * 64 + j];
      s2 += pb[c + 2] * w1s[(c + 2) * 64 + j];
      s3 += pb[c + 3] * w1s[(c + 3) * 64 + j];
    }
    hs[task] = fmaxf((s0 + s1) + (s2 + s3) + b1[j], 0.f);
  }
  __syncthreads();
  if (t < 128) {
    int b = t >> 2, k = t & 3;
    float s = b2[k];
    const float* hb = hs + b * 64;
#pragma unroll 4
    for (int j = 0; j < 64; ++j) s += hb[j] * w2[j * 4 + k];
    lg[t] = s * (1.0f / 30.0f);
  }
  __syncthreads();
  if (t < 32) {
    int b = t;
    float z0 = lg[b*4], z1 = lg[b*4+1], z2 = lg[b*4+2], z3 = lg[b*4+3];
    float m = fmaxf(fmaxf(z0, z1), fmaxf(z2, z3));
    float e0 = expf(z0-m), e1 = expf(z1-m), e2 = expf(z2-m), e3 = expf(z3-m);
    float inv = 1.0f / (e0 + e1 + e2 + e3);
    at[b*4] = e0*inv; at[b*4+1] = e1*inv; at[b*4+2] = e2*inv; at[b*4+3] = e3*inv;
    attn[b*4] = at[b*4]; attn[b*4+1] = at[b*4+1];
    attn[b*4+2] = at[b*4+2]; attn[b*4+3] = at[b*4+3];
  }
  __syncthreads();
  for (int i = t; i < 8192; i += 256) {
    int b = i >> 8, f = i & 255;
    biasagg[i] = at[b*4]*biases[f] + at[b*4+1]*biases[256+f]
               + at[b*4+2]*biases[512+f] + at[b*4+3]*biases[768+f];
  }
}

// ---------------- kernel 3: weight aggregation + transpose to [b][tap][f][c] ----------------
// v3: one block per (xcd, cq, tap) computes all 4 b's owned by that XCD in conv's
// swizzle (b = 4*xcd..4*xcd+3). Kernel-tensor reads drop 288MB -> 72MB, and wagg[b]
// is written on the same XCD that conv reads it from (L2 producer-consumer locality).
// LDS: 4 tiles [64][260] bf16 = 133,120 B -> 1 block/CU.
__global__ __launch_bounds__(256)
void wagg_kernel(const float* __restrict__ kers, const float* __restrict__ attn,
                 bf16_t* __restrict__ wagg) {
  const int lid   = blockIdx.x;   // 0..287
  const int xcd   = lid & 7;
  const int slice = lid >> 3;     // 0..35
  const int cq  = slice & 3;
  const int tap = slice >> 2;     // 0..8
  const int b0  = xcd << 2;
  const int t   = threadIdx.x;
  __shared__ bf16_t tile[4][64 * 260];

  float a[4][4];
#pragma unroll
  for (int i = 0; i < 4; ++i)
#pragma unroll
    for (int k = 0; k < 4; ++k) a[i][k] = attn[(b0 + i) * 4 + k];

  const float* k0 = kers + ((size_t)(0 * 9 + tap)) * 65536;
  const float* k1 = kers + ((size_t)(1 * 9 + tap)) * 65536;
  const float* k2 = kers + ((size_t)(2 * 9 + tap)) * 65536;
  const float* k3 = kers + ((size_t)(3 * 9 + tap)) * 65536;

  const int fq = t & 63;       // f group: f0 = fq*4
  const int cl = t >> 6;       // 0..3
  const int f0 = fq * 4;
#pragma unroll
  for (int pass = 0; pass < 16; ++pass) {
    const int c_local = pass * 4 + cl;           // 0..63
    const size_t o = (size_t)(cq * 64 + c_local) * 256 + f0;
    floatx4 v0 = *(const floatx4*)(k0 + o);
    floatx4 v1 = *(const floatx4*)(k1 + o);
    floatx4 v2 = *(const floatx4*)(k2 + o);
    floatx4 v3 = *(const floatx4*)(k3 + o);
#pragma unroll
    for (int i = 0; i < 4; ++i) {
      bf16x4 r;
#pragma unroll
      for (int j = 0; j < 4; ++j)
        r[j] = (bf16_t)(a[i][0] * v0[j] + a[i][1] * v1[j] + a[i][2] * v2[j] + a[i][3] * v3[j]);
      *(bf16x4*)&tile[i][c_local * 260 + f0] = r;   // 8B write, 8-aligned (520B rows)
    }
  }
  __syncthreads();

#pragma unroll
  for (int i = 0; i < 4; ++i) {
    bf16_t* wt = wagg + ((size_t)((b0 + i) * 9 + tap)) * 65536 + cq * 64;
#pragma unroll
    for (int pass = 0; pass < 8; ++pass) {
      const int gi = pass * 256 + t;               // 0..2047
      const int f  = gi >> 3;                      // 0..255
      const int cg = gi & 7;                       // 0..7  (8-c granule)
      bf16x8 v;
#pragma unroll
      for (int jj = 0; jj < 8; ++jj) v[jj] = tile[i][(cg * 8 + jj) * 260 + f];
      *(bf16x8*)(wt + (size_t)f * 256 + cg * 8) = v;  // 16B store, 16-aligned
    }
  }
}

// ---------------- kernel 4: implicit-GEMM conv with per-sample weights ----------------
// tile: 8h x 14w (M=112) x 256f; 4 waves of 112x64; K = 4 cq * 9 tap * 2 ks * 32
// v3: triple-buffered B stages + raw s_barrier + counted s_waitcnt vmcnt(4)
// (T3/T4: staging loads stay in flight across the barrier, no per-step vmcnt(0)
// drain). Patch buffer single (rewritten only at the 3 cq transitions, guarded by
// an extra barrier). XCD-aware block swizzle: each XCD owns 4 consecutive b's.
#define PBUF_BYTES 20480   // 160 pos * 8 granules * 16B
#define BBUF_BYTES 16384   // 256 f * 4 granules * 16B

__global__ __launch_bounds__(256, 2)
void conv_mfma(const bf16_t* __restrict__ xpad, const bf16_t* __restrict__ wagg,
               const float* __restrict__ biasagg, float* __restrict__ out) {
  __shared__ char lds[PBUF_BYTES + 3 * BBUF_BYTES];  // 69632 B
  char* ldsP = lds;
  char* ldsB = lds + PBUF_BYTES;

  // XCD swizzle: 896 blocks, 896 % 8 == 0 -> bijective chunked remap.
  const int lid  = blockIdx.y * 28 + blockIdx.x;       // hw dispatch order
  const int nid  = (lid & 7) * 112 + (lid >> 3);       // per-XCD contiguous work
  const int b    = nid / 28;
  const int tile = nid - b * 28;
  const int h0 = (tile >> 2) * 8;
  const int w0 = (tile & 3) * 14;

  const int tid  = threadIdx.x;
  const int lane = tid & 63;
  const int wv   = tid >> 6;
  const int l15  = lane & 15;
  const int quad = lane >> 4;
  const int n0   = wv * 64;

  const char* xb = (const char*)xpad + (size_t)b * (HP * WP * 256 * 2);
  const char* wb = (const char*)wagg + (size_t)b * (9 * 256 * 256 * 2);

  // static per-lane offsets
  int offs[7];
#pragma unroll
  for (int mi = 0; mi < 7; ++mi) {
    int m = mi * 16 + l15;
    int ty = m / 14;
    int tx = m - ty * 14;
    offs[mi] = ty * 16 + tx;   // patch position index
  }
  int boff[4];
#pragma unroll
  for (int ni = 0; ni < 4; ++ni) {
    int f = n0 + ni * 16 + l15;
    boff[ni] = f * 64 + ((quad ^ ((f >> 1) & 3)) << 4);  // swizzled granule
  }

  floatx4 acc[7][4];
#pragma unroll
  for (int mi = 0; mi < 7; ++mi)
#pragma unroll
    for (int ni = 0; ni < 4; ++ni) acc[mi][ni] = (floatx4){0.f, 0.f, 0.f, 0.f};

  auto stage_patch = [&](int cq) {
#pragma unroll
    for (int ii = 0; ii < 5; ++ii) {
      int i20 = wv * 5 + ii;            // 0..19, wave-uniform
      int p = i20 * 8 + (lane >> 3);    // patch position 0..159
      int gsrc = (lane & 7) ^ (p & 7);  // XOR swizzle
      const char* src = xb + ((size_t)((h0 + (p >> 4)) * WP + (w0 + (p & 15))) * 512)
                           + cq * 128 + gsrc * 16;
      async_copy16(src, ldsP + i20 * 1024);
    }
  };
  auto stage_b = [&](int cq, int tap, int ks, int slot) {
    const char* wt = wb + (size_t)tap * (256 * 256 * 2);
    int kbyte = cq * 128 + ks * 64;
#pragma unroll
    for (int ii = 0; ii < 4; ++ii) {
      int i16 = wv * 4 + ii;            // 0..15, wave-uniform
      int f = i16 * 16 + (lane >> 2);
      int gsrc = (lane & 3) ^ ((f >> 1) & 3);
      const char* src = wt + f * 512 + kbyte + gsrc * 16;
      async_copy16(src, ldsB + slot * BBUF_BYTES + i16 * 1024);
    }
  };

  // prologue: patch for cq0 + first B tile. No barrier here; iter 0's counted
  // wait + barrier covers both (vmcnt(4) leaves only the newest stage in flight).
  stage_patch(0);
  stage_b(0, 0, 0, 0);

  int cq = 0, tap = 0, ks = 0;
  int bcur = 0, bnxt = 1;
  while (true) {
    int nks = ks + 1, ntap = tap, ncq = cq;
    if (nks == 2) { nks = 0; ++ntap; if (ntap == 9) { ntap = 0; ++ncq; } }
    const bool have_next = (ncq < 4);
    if (have_next) {
      stage_b(ncq, ntap, nks, bnxt);
      // wait for everything except the 4 loads just issued: B[cur] (and, on the
      // iteration after a cq transition, the 5 patch loads) are older in FIFO.
      asm volatile("s_waitcnt vmcnt(4)" ::: "memory");
    } else {
      asm volatile("s_waitcnt vmcnt(0)" ::: "memory");
    }
    __builtin_amdgcn_s_barrier();
    __builtin_amdgcn_sched_barrier(0);
    {
      const char* pc = ldsP;
      const char* bc = ldsB + bcur * BBUF_BYTES;
      const int tapoff = (tap / 3) * 16 + (tap % 3);
      const int gA = ks * 4 + quad;
      bf16x8 a[7];
#pragma unroll
      for (int mi = 0; mi < 7; ++mi) {
        int p = offs[mi] + tapoff;
        int addr = (p << 7) + ((gA ^ (p & 7)) << 4);
        a[mi] = *(const bf16x8*)(pc + addr);
      }
      bf16x8 bv[4];
#pragma unroll
      for (int ni = 0; ni < 4; ++ni) bv[ni] = *(const bf16x8*)(bc + boff[ni]);
#pragma unroll
      for (int mi = 0; mi < 7; ++mi)
#pragma unroll
        for (int ni = 0; ni < 4; ++ni)
          acc[mi][ni] = __builtin_amdgcn_mfma_f32_16x16x32_bf16(a[mi], bv[ni], acc[mi][ni], 0, 0, 0);
    }
    if (!have_next) break;
    if (ncq != cq) {
      // all waves must finish reading the old patch before overwrite
      __builtin_amdgcn_s_barrier();
      stage_patch(ncq);   // 5 loads, older than next iter's B stage -> covered by vmcnt(4)
    }
    cq = ncq; tap = ntap; ks = nks;
    bcur = bnxt; bnxt = bnxt + 1; if (bnxt == 3) bnxt = 0;
  }

  // epilogue: D layout col=lane&15 (f), row=quad*4+reg (m)
  float bias[4];
#pragma unroll
  for (int ni = 0; ni < 4; ++ni) bias[ni] = biasagg[b * 256 + n0 + ni * 16 + l15];
  float* outb = out + (size_t)b * (56 * 56 * 256);
#pragma unroll
  for (int mi = 0; mi < 7; ++mi) {
#pragma unroll
    for (int rg = 0; rg < 4; ++rg) {
      int m = mi * 16 + quad * 4 + rg;
      int ty = m / 14, tx = m - ty * 14;
      float* orow = outb + ((size_t)((h0 + ty) * 56) + (w0 + tx)) * 256 + n0 + l15;
#pragma unroll
      for (int ni = 0; ni < 4; ++ni) orow[ni * 16] = acc[mi][ni][rg] + bias[ni];
    }
  }
}

extern "C" void kernel_launch(void* const* d_in, const int* in_sizes, int n_in,
                              void* d_out, int out_size, void* d_ws, size_t ws_size,
                              hipStream_t stream) {
  const float* x      = (const float*)d_in[0];
  const float* kers   = (const float*)d_in[1];
  const float* biases = (const float*)d_in[2];
  const float* w1     = (const float*)d_in[3];
  const float* b1     = (const float*)d_in[4];
  const float* w2     = (const float*)d_in[5];
  const float* b2     = (const float*)d_in[6];
  float* outp = (float*)d_out;
  char* ws = (char*)d_ws;

  bf16_t* xpad   = (bf16_t*)(ws + XPAD_OFF);
  bf16_t* wagg   = (bf16_t*)(ws + WAGG_OFF);
  float* pooled  = (float*)(ws + POOLED_OFF);
  float* attn    = (float*)(ws + ATTN_OFF);
  float* biasagg = (float*)(ws + BIASAGG_OFF);

  hipMemsetAsync(pooled, 0, 32 * 256 * sizeof(float), stream);
  pad_pool<<<dim3(58, 32), 256, 0, stream>>>(x, xpad, pooled);
  router<<<1, 256, 0, stream>>>(pooled, w1, b1, w2, b2, biases, attn, biasagg);
  wagg_kernel<<<dim3(288), 256, 0, stream>>>(kers, attn, wagg);
  conv_mfma<<<dim3(28, 32), 256, 0, stream>>>(xpad, wagg, biasagg, outp);
}

// Round 2
// 371.727 us; speedup vs baseline: 1.0362x; 1.0260x over previous
//
#include <hip/hip_runtime.h>
#include <hip/hip_bf16.h>
#include <stdint.h>

typedef __bf16 bf16_t;
typedef __bf16 bf16x4 __attribute__((ext_vector_type(4)));
typedef __bf16 bf16x8 __attribute__((ext_vector_type(8)));
typedef float floatx4 __attribute__((ext_vector_type(4)));

#define B_ 32
#define HP 58
#define WP 66

// ws layout (bytes)
#define XPAD_OFF   0u
#define WAGG_OFF   62717952u     // 32*58*66*256*2
#define POOLED_OFF 100466688u    // + 32*9*256*256*2
#define ATTN_OFF   100499456u
#define BIASAGG_OFF 100499968u

__device__ __forceinline__ void async_copy16(const void* gsrc, void* ldst) {
  __builtin_amdgcn_global_load_lds(
      (const __attribute__((address_space(1))) unsigned int*)gsrc,
      (__attribute__((address_space(3))) unsigned int*)ldst, 16, 0, 0);
}

// ---------------- kernel 1: pad + convert + GAP partial sums ----------------
__global__ __launch_bounds__(256)
void pad_pool(const float* __restrict__ x, bf16_t* __restrict__ xpad,
              float* __restrict__ pooled) {
  const int hp = blockIdx.x;   // 0..57
  const int b  = blockIdx.y;
  const int t  = threadIdx.x;
  const int c4 = (t & 63) << 2;   // 0..252 (float4 channel group)
  const int wq = t >> 6;          // 0..3
  const int h  = hp - 1;
  const bool hvalid = (h >= 0) && (h < 56);
  bf16_t* dst = xpad + ((size_t)(b * 58 + hp)) * (66 * 256);
  const float* srcrow = x + ((size_t)(b * 56 + (hvalid ? h : 0))) * (56 * 256);
  floatx4 sum = {0.f, 0.f, 0.f, 0.f};
  for (int wp = wq; wp < 66; wp += 4) {
    const int w = wp - 1;
    floatx4 v = {0.f, 0.f, 0.f, 0.f};
    if (hvalid && (unsigned)w < 56u) {
      v = *(const floatx4*)(srcrow + w * 256 + c4);
      sum += v;
    }
    bf16x4 r;
#pragma unroll
    for (int j = 0; j < 4; ++j) r[j] = (bf16_t)v[j];
    *(bf16x4*)(dst + wp * 256 + c4) = r;
  }
  __shared__ floatx4 red[4][64];
  red[wq][t & 63] = sum;
  __syncthreads();
  if (hvalid && t < 64) {
    floatx4 s = red[0][t] + red[1][t] + red[2][t] + red[3][t];
#pragma unroll
    for (int j = 0; j < 4; ++j) atomicAdd(&pooled[b * 256 + t * 4 + j], s[j]);
  }
}

// ---------------- kernel 2: router MLP + softmax + bias agg ----------------
__global__ __launch_bounds__(256)
void router(const float* __restrict__ pooled, const float* __restrict__ w1,
            const float* __restrict__ b1, const float* __restrict__ w2,
            const float* __restrict__ b2, const float* __restrict__ biases,
            float* __restrict__ attn, float* __restrict__ biasagg) {
  __shared__ float ps[8192];
  __shared__ float w1s[16384];
  __shared__ float hs[2048];
  __shared__ float lg[128];
  __shared__ float at[128];
  const int t = threadIdx.x;
  for (int i = t; i < 8192; i += 256) ps[i] = pooled[i] * (1.0f / 3136.0f);
  for (int i = t; i < 4096; i += 256)
    *(floatx4*)&w1s[i * 4] = *(const floatx4*)&w1[i * 4];
  __syncthreads();
  for (int task = t; task < 2048; task += 256) {
    const int b = task >> 6, j = task & 63;
    const float* pb = ps + b * 256;
    float s0 = 0.f, s1 = 0.f, s2 = 0.f, s3 = 0.f;
#pragma unroll 4
    for (int c = 0; c < 256; c += 4) {
      s0 += pb[c]     * w1s[c * 64 + j];
      s1 += pb[c + 1] * w1s[(c + 1) * 64 + j];
      s2 += pb[c + 2] * w1s[(c + 2) * 64 + j];
      s3 += pb[c + 3] * w1s[(c + 3) * 64 + j];
    }
    hs[task] = fmaxf((s0 + s1) + (s2 + s3) + b1[j], 0.f);
  }
  __syncthreads();
  if (t < 128) {
    int b = t >> 2, k = t & 3;
    float s = b2[k];
    const float* hb = hs + b * 64;
#pragma unroll 4
    for (int j = 0; j < 64; ++j) s += hb[j] * w2[j * 4 + k];
    lg[t] = s * (1.0f / 30.0f);
  }
  __syncthreads();
  if (t < 32) {
    int b = t;
    float z0 = lg[b*4], z1 = lg[b*4+1], z2 = lg[b*4+2], z3 = lg[b*4+3];
    float m = fmaxf(fmaxf(z0, z1), fmaxf(z2, z3));
    float e0 = expf(z0-m), e1 = expf(z1-m), e2 = expf(z2-m), e3 = expf(z3-m);
    float inv = 1.0f / (e0 + e1 + e2 + e3);
    at[b*4] = e0*inv; at[b*4+1] = e1*inv; at[b*4+2] = e2*inv; at[b*4+3] = e3*inv;
    attn[b*4] = at[b*4]; attn[b*4+1] = at[b*4+1];
    attn[b*4+2] = at[b*4+2]; attn[b*4+3] = at[b*4+3];
  }
  __syncthreads();
  for (int i = t; i < 8192; i += 256) {
    int b = i >> 8, f = i & 255;
    biasagg[i] = at[b*4]*biases[f] + at[b*4+1]*biases[256+f]
               + at[b*4+2]*biases[512+f] + at[b*4+3]*biases[768+f];
  }
}

// ---------------- kernel 3: weight aggregation + transpose to [b][tap][f][c] ----------------
// v4: one block per (xcd, c-32-chunk, tap) computes the 4 b's owned by that XCD in
// conv's swizzle. Reads stay 74MB (4x dedup), LDS 66.5KB -> 2 blocks/CU, 576 blocks.
__global__ __launch_bounds__(256)
void wagg_kernel(const float* __restrict__ kers, const float* __restrict__ attn,
                 bf16_t* __restrict__ wagg) {
  const int lid = blockIdx.x;     // 0..575
  const int xcd = lid & 7;
  const int sl  = lid >> 3;       // 0..71
  const int c8  = sl & 7;         // 32-channel chunk: c0 = c8*32
  const int tap = sl >> 3;        // 0..8
  const int b0  = xcd << 2;
  const int t   = threadIdx.x;
  __shared__ bf16_t tile[4][32 * 260];

  float a[4][4];
#pragma unroll
  for (int i = 0; i < 4; ++i)
#pragma unroll
    for (int k = 0; k < 4; ++k) a[i][k] = attn[(b0 + i) * 4 + k];

  const float* k0 = kers + ((size_t)(0 * 9 + tap)) * 65536 + (size_t)(c8 * 32) * 256;
  const float* k1 = kers + ((size_t)(1 * 9 + tap)) * 65536 + (size_t)(c8 * 32) * 256;
  const float* k2 = kers + ((size_t)(2 * 9 + tap)) * 65536 + (size_t)(c8 * 32) * 256;
  const float* k3 = kers + ((size_t)(3 * 9 + tap)) * 65536 + (size_t)(c8 * 32) * 256;

  const int fq = t & 63;       // f group: f0 = fq*4
  const int cl = t >> 6;       // 0..3
  const int f0 = fq * 4;
#pragma unroll
  for (int pass = 0; pass < 8; ++pass) {
    const int c_local = pass * 4 + cl;           // 0..31
    const size_t o = (size_t)c_local * 256 + f0;
    floatx4 v0 = *(const floatx4*)(k0 + o);
    floatx4 v1 = *(const floatx4*)(k1 + o);
    floatx4 v2 = *(const floatx4*)(k2 + o);
    floatx4 v3 = *(const floatx4*)(k3 + o);
#pragma unroll
    for (int i = 0; i < 4; ++i) {
      bf16x4 r;
#pragma unroll
      for (int j = 0; j < 4; ++j)
        r[j] = (bf16_t)(a[i][0] * v0[j] + a[i][1] * v1[j] + a[i][2] * v2[j] + a[i][3] * v3[j]);
      *(bf16x4*)&tile[i][c_local * 260 + f0] = r;   // 8B write, 8-aligned
    }
  }
  __syncthreads();

#pragma unroll
  for (int i = 0; i < 4; ++i) {
    bf16_t* wt = wagg + ((size_t)((b0 + i) * 9 + tap)) * 65536 + c8 * 32;
#pragma unroll
    for (int pass = 0; pass < 4; ++pass) {
      const int gi = pass * 256 + t;               // 0..1023
      const int f  = gi >> 2;                      // 0..255
      const int cg = gi & 3;                       // 0..3  (8-c granule within chunk)
      bf16x8 v;
#pragma unroll
      for (int jj = 0; jj < 8; ++jj) v[jj] = tile[i][(cg * 8 + jj) * 260 + f];
      *(bf16x8*)(wt + (size_t)f * 256 + cg * 8) = v;  // 16B store, 16-aligned
    }
  }
}

// ---------------- kernel 4: implicit-GEMM conv with per-sample weights ----------------
// v4: register-level A-fragment prefetch across K-steps (double-step unrolled loop
// with aA/aB ping-pong), per-tap A address compute (ks=1 = ks=0 XOR 64),
// loop-invariant staging offsets, setprio around MFMA cluster. Triple-buffered B
// with counted vmcnt(4) kept from v3.
#define PBUF_BYTES 20480   // 160 pos * 8 granules * 16B
#define BBUF_BYTES 16384   // 256 f * 4 granules * 16B

__global__ __launch_bounds__(256, 2)
void conv_mfma(const bf16_t* __restrict__ xpad, const bf16_t* __restrict__ wagg,
               const float* __restrict__ biasagg, float* __restrict__ out) {
  __shared__ char lds[PBUF_BYTES + 3 * BBUF_BYTES];  // 69632 B
  char* ldsP = lds;
  char* ldsB = lds + PBUF_BYTES;

  // XCD swizzle: 896 blocks, 896 % 8 == 0 -> bijective chunked remap.
  const int lid  = blockIdx.y * 28 + blockIdx.x;       // hw dispatch order
  const int nid  = (lid & 7) * 112 + (lid >> 3);       // per-XCD contiguous work
  const int b    = nid / 28;
  const int tile = nid - b * 28;
  const int h0 = (tile >> 2) * 8;
  const int w0 = (tile & 3) * 14;

  const int tid  = threadIdx.x;
  const int lane = tid & 63;
  const int wv   = tid >> 6;
  const int l15  = lane & 15;
  const int quad = lane >> 4;
  const int n0   = wv * 64;

  const char* xb = (const char*)xpad + (size_t)b * (HP * WP * 256 * 2);
  const char* wb = (const char*)wagg + (size_t)b * (9 * 256 * 256 * 2);

  // static per-lane offsets
  int offs[7];
#pragma unroll
  for (int mi = 0; mi < 7; ++mi) {
    int m = mi * 16 + l15;
    int ty = m / 14;
    int tx = m - ty * 14;
    offs[mi] = ty * 16 + tx;   // patch position index
  }
  int boff[4];
#pragma unroll
  for (int ni = 0; ni < 4; ++ni) {
    int f = n0 + ni * 16 + l15;
    boff[ni] = f * 64 + ((quad ^ ((f >> 1) & 3)) << 4);  // swizzled granule
  }
  // loop-invariant staging offsets (per-lane)
  int sb_off[4], sb_lds[4];
#pragma unroll
  for (int ii = 0; ii < 4; ++ii) {
    int i16 = wv * 4 + ii;
    int f = i16 * 16 + (lane >> 2);
    int gsrc = (lane & 3) ^ ((f >> 1) & 3);
    sb_off[ii] = f * 512 + gsrc * 16;
    sb_lds[ii] = i16 * 1024;
  }
  int sp_off[5], sp_lds[5];
#pragma unroll
  for (int ii = 0; ii < 5; ++ii) {
    int i20 = wv * 5 + ii;
    int p = i20 * 8 + (lane >> 3);
    int gsrc = (lane & 7) ^ (p & 7);
    sp_off[ii] = ((h0 + (p >> 4)) * WP + (w0 + (p & 15))) * 512 + gsrc * 16;
    sp_lds[ii] = i20 * 1024;
  }

  floatx4 acc[7][4];
#pragma unroll
  for (int mi = 0; mi < 7; ++mi)
#pragma unroll
    for (int ni = 0; ni < 4; ++ni) acc[mi][ni] = (floatx4){0.f, 0.f, 0.f, 0.f};

  auto stage_patch = [&](int cq) {
#pragma unroll
    for (int ii = 0; ii < 5; ++ii)
      async_copy16(xb + cq * 128 + sp_off[ii], ldsP + sp_lds[ii]);
  };
  auto stage_b = [&](int tap, int kbyte, int slot) {
    const char* wtb = wb + (size_t)tap * 131072 + kbyte;
#pragma unroll
    for (int ii = 0; ii < 4; ++ii)
      async_copy16(wtb + sb_off[ii], ldsB + slot * BBUF_BYTES + sb_lds[ii]);
  };

  stage_patch(0);
  stage_b(0, 0, 0);

  bf16x8 aA[7], aB[7];
  int aoff[7];
  int slot = 0;

#pragma unroll 1
  for (int d = 0; d < 36; ++d) {
    const int cq  = d / 9;
    const int tap = d - cq * 9;
    const int s1 = (slot == 2) ? 0 : slot + 1;
    const int s2 = (s1 == 2) ? 0 : s1 + 1;

    // ================ even half: ks=0, tile in `slot` ================
    stage_b(tap, cq * 128 + 64, s1);                 // tile (cq,tap,ks=1)
    asm volatile("s_waitcnt vmcnt(4)" ::: "memory");
    __builtin_amdgcn_s_barrier();
    __builtin_amdgcn_sched_barrier(0);
    {
      const char* bc = ldsB + slot * BBUF_BYTES;
      bf16x8 bv0 = *(const bf16x8*)(bc + boff[0]);
      bf16x8 bv1 = *(const bf16x8*)(bc + boff[1]);
      bf16x8 bv2 = *(const bf16x8*)(bc + boff[2]);
      bf16x8 bv3 = *(const bf16x8*)(bc + boff[3]);
      if (tap == 0) {
        const int tapoff = 0;
#pragma unroll
        for (int mi = 0; mi < 7; ++mi) {
          int p = offs[mi] + tapoff;
          aoff[mi] = (p << 7) + ((quad ^ (p & 7)) << 4);
          aA[mi] = *(const bf16x8*)(ldsP + aoff[mi]);
        }
      }
      // prefetch ks=1 fragments (same patch, granule XOR 64)
#pragma unroll
      for (int mi = 0; mi < 7; ++mi)
        aB[mi] = *(const bf16x8*)(ldsP + (aoff[mi] ^ 64));
      __builtin_amdgcn_s_setprio(1);
#pragma unroll
      for (int mi = 0; mi < 7; ++mi) {
        acc[mi][0] = __builtin_amdgcn_mfma_f32_16x16x32_bf16(aA[mi], bv0, acc[mi][0], 0, 0, 0);
        acc[mi][1] = __builtin_amdgcn_mfma_f32_16x16x32_bf16(aA[mi], bv1, acc[mi][1], 0, 0, 0);
        acc[mi][2] = __builtin_amdgcn_mfma_f32_16x16x32_bf16(aA[mi], bv2, acc[mi][2], 0, 0, 0);
        acc[mi][3] = __builtin_amdgcn_mfma_f32_16x16x32_bf16(aA[mi], bv3, acc[mi][3], 0, 0, 0);
      }
      __builtin_amdgcn_s_setprio(0);
    }

    // ================ odd half: ks=1, tile in `s1` ================
    const bool last = (d == 35);
    if (!last) {
      const int ntap = (tap == 8) ? 0 : tap + 1;
      const int ncq  = (tap == 8) ? cq + 1 : cq;
      stage_b(ntap, ncq * 128, s2);                  // tile (ncq,ntap,ks=0)
      asm volatile("s_waitcnt vmcnt(4)" ::: "memory");
    } else {
      asm volatile("s_waitcnt vmcnt(0)" ::: "memory");
    }
    __builtin_amdgcn_s_barrier();
    __builtin_amdgcn_sched_barrier(0);
    {
      const char* bc = ldsB + s1 * BBUF_BYTES;
      bf16x8 bv0 = *(const bf16x8*)(bc + boff[0]);
      bf16x8 bv1 = *(const bf16x8*)(bc + boff[1]);
      bf16x8 bv2 = *(const bf16x8*)(bc + boff[2]);
      bf16x8 bv3 = *(const bf16x8*)(bc + boff[3]);
      __builtin_amdgcn_s_setprio(1);
#pragma unroll
      for (int mi = 0; mi < 7; ++mi) {
        acc[mi][0] = __builtin_amdgcn_mfma_f32_16x16x32_bf16(aB[mi], bv0, acc[mi][0], 0, 0, 0);
        acc[mi][1] = __builtin_amdgcn_mfma_f32_16x16x32_bf16(aB[mi], bv1, acc[mi][1], 0, 0, 0);
        acc[mi][2] = __builtin_amdgcn_mfma_f32_16x16x32_bf16(aB[mi], bv2, acc[mi][2], 0, 0, 0);
        acc[mi][3] = __builtin_amdgcn_mfma_f32_16x16x32_bf16(aB[mi], bv3, acc[mi][3], 0, 0, 0);
      }
      __builtin_amdgcn_s_setprio(0);
      if (tap < 8) {
        // compute next tap's A offsets + prefetch its ks=0 fragments (same patch)
        const int ntapoff = ((tap + 1) / 3) * 16 + ((tap + 1) % 3);
#pragma unroll
        for (int mi = 0; mi < 7; ++mi) {
          int p = offs[mi] + ntapoff;
          aoff[mi] = (p << 7) + ((quad ^ (p & 7)) << 4);
          aA[mi] = *(const bf16x8*)(ldsP + aoff[mi]);
        }
      } else if (!last) {
        // cq transition: all waves done reading old patch -> restage
        __builtin_amdgcn_s_barrier();
        stage_patch(cq + 1);
      }
    }
    slot = s2;
  }

  // epilogue: D layout col=lane&15 (f), row=quad*4+reg (m)
  float bias[4];
#pragma unroll
  for (int ni = 0; ni < 4; ++ni) bias[ni] = biasagg[b * 256 + n0 + ni * 16 + l15];
  float* outb = out + (size_t)b * (56 * 56 * 256);
#pragma unroll
  for (int mi = 0; mi < 7; ++mi) {
#pragma unroll
    for (int rg = 0; rg < 4; ++rg) {
      int m = mi * 16 + quad * 4 + rg;
      int ty = m / 14, tx = m - ty * 14;
      float* orow = outb + ((size_t)((h0 + ty) * 56) + (w0 + tx)) * 256 + n0 + l15;
#pragma unroll
      for (int ni = 0; ni < 4; ++ni) orow[ni * 16] = acc[mi][ni][rg] + bias[ni];
    }
  }
}

extern "C" void kernel_launch(void* const* d_in, const int* in_sizes, int n_in,
                              void* d_out, int out_size, void* d_ws, size_t ws_size,
                              hipStream_t stream) {
  const float* x      = (const float*)d_in[0];
  const float* kers   = (const float*)d_in[1];
  const float* biases = (const float*)d_in[2];
  const float* w1     = (const float*)d_in[3];
  const float* b1     = (const float*)d_in[4];
  const float* w2     = (const float*)d_in[5];
  const float* b2     = (const float*)d_in[6];
  float* outp = (float*)d_out;
  char* ws = (char*)d_ws;

  bf16_t* xpad   = (bf16_t*)(ws + XPAD_OFF);
  bf16_t* wagg   = (bf16_t*)(ws + WAGG_OFF);
  float* pooled  = (float*)(ws + POOLED_OFF);
  float* attn    = (float*)(ws + ATTN_OFF);
  float* biasagg = (float*)(ws + BIASAGG_OFF);

  hipMemsetAsync(pooled, 0, 32 * 256 * sizeof(float), stream);
  pad_pool<<<dim3(58, 32), 256, 0, stream>>>(x, xpad, pooled);
  router<<<1, 256, 0, stream>>>(pooled, w1, b1, w2, b2, biases, attn, biasagg);
  wagg_kernel<<<dim3(576), 256, 0, stream>>>(kers, attn, wagg);
  conv_mfma<<<dim3(28, 32), 256, 0, stream>>>(xpad, wagg, biasagg, outp);
}

// Round 3
// 361.773 us; speedup vs baseline: 1.0647x; 1.0275x over previous
//
#include <hip/hip_runtime.h>
#include <hip/hip_bf16.h>
#include <stdint.h>

typedef __bf16 bf16_t;
typedef __bf16 bf16x4 __attribute__((ext_vector_type(4)));
typedef __bf16 bf16x8 __attribute__((ext_vector_type(8)));
typedef float floatx4 __attribute__((ext_vector_type(4)));

#define B_ 32
#define HP 58
#define WP 66

// ws layout (bytes)
#define XPAD_OFF   0u
#define WAGG_OFF   62717952u     // 32*58*66*256*2
#define POOLED_OFF 100466688u    // + 32*9*256*256*2
#define ATTN_OFF   100499456u
#define BIASAGG_OFF 100499968u

__device__ __forceinline__ void async_copy16(const void* gsrc, void* ldst) {
  __builtin_amdgcn_global_load_lds(
      (const __attribute__((address_space(1))) unsigned int*)gsrc,
      (__attribute__((address_space(3))) unsigned int*)ldst, 16, 0, 0);
}

// ---------------- kernel 1: pad + convert + GAP partial sums ----------------
__global__ __launch_bounds__(256)
void pad_pool(const float* __restrict__ x, bf16_t* __restrict__ xpad,
              float* __restrict__ pooled) {
  const int hp = blockIdx.x;   // 0..57
  const int b  = blockIdx.y;
  const int t  = threadIdx.x;
  const int c4 = (t & 63) << 2;   // 0..252 (float4 channel group)
  const int wq = t >> 6;          // 0..3
  const int h  = hp - 1;
  const bool hvalid = (h >= 0) && (h < 56);
  bf16_t* dst = xpad + ((size_t)(b * 58 + hp)) * (66 * 256);
  const float* srcrow = x + ((size_t)(b * 56 + (hvalid ? h : 0))) * (56 * 256);
  floatx4 sum = {0.f, 0.f, 0.f, 0.f};
  for (int wp = wq; wp < 66; wp += 4) {
    const int w = wp - 1;
    floatx4 v = {0.f, 0.f, 0.f, 0.f};
    if (hvalid && (unsigned)w < 56u) {
      v = *(const floatx4*)(srcrow + w * 256 + c4);
      sum += v;
    }
    bf16x4 r;
#pragma unroll
    for (int j = 0; j < 4; ++j) r[j] = (bf16_t)v[j];
    *(bf16x4*)(dst + wp * 256 + c4) = r;
  }
  __shared__ floatx4 red[4][64];
  red[wq][t & 63] = sum;
  __syncthreads();
  if (hvalid && t < 64) {
    floatx4 s = red[0][t] + red[1][t] + red[2][t] + red[3][t];
#pragma unroll
    for (int j = 0; j < 4; ++j) atomicAdd(&pooled[b * 256 + t * 4 + j], s[j]);
  }
}

// ---------------- kernel 2: router MLP + softmax + bias agg ----------------
__global__ __launch_bounds__(256)
void router(const float* __restrict__ pooled, const float* __restrict__ w1,
            const float* __restrict__ b1, const float* __restrict__ w2,
            const float* __restrict__ b2, const float* __restrict__ biases,
            float* __restrict__ attn, float* __restrict__ biasagg) {
  __shared__ float ps[8192];
  __shared__ float w1s[16384];
  __shared__ float hs[2048];
  __shared__ float lg[128];
  __shared__ float at[128];
  const int t = threadIdx.x;
  for (int i = t; i < 8192; i += 256) ps[i] = pooled[i] * (1.0f / 3136.0f);
  for (int i = t; i < 4096; i += 256)
    *(floatx4*)&w1s[i * 4] = *(const floatx4*)&w1[i * 4];
  __syncthreads();
  for (int task = t; task < 2048; task += 256) {
    const int b = task >> 6, j = task & 63;
    const float* pb = ps + b * 256;
    float s0 = 0.f, s1 = 0.f, s2 = 0.f, s3 = 0.f;
#pragma unroll 4
    for (int c = 0; c < 256; c += 4) {
      s0 += pb[c]     * w1s[c * 64 + j];
      s1 += pb[c + 1] * w1s[(c + 1) * 64 + j];
      s2 += pb[c + 2] * w1s[(c + 2) * 64 + j];
      s3 += pb[c + 3] * w1s[(c + 3) * 64 + j];
    }
    hs[task] = fmaxf((s0 + s1) + (s2 + s3) + b1[j], 0.f);
  }
  __syncthreads();
  if (t < 128) {
    int b = t >> 2, k = t & 3;
    float s = b2[k];
    const float* hb = hs + b * 64;
#pragma unroll 4
    for (int j = 0; j < 64; ++j) s += hb[j] * w2[j * 4 + k];
    lg[t] = s * (1.0f / 30.0f);
  }
  __syncthreads();
  if (t < 32) {
    int b = t;
    float z0 = lg[b*4], z1 = lg[b*4+1], z2 = lg[b*4+2], z3 = lg[b*4+3];
    float m = fmaxf(fmaxf(z0, z1), fmaxf(z2, z3));
    float e0 = expf(z0-m), e1 = expf(z1-m), e2 = expf(z2-m), e3 = expf(z3-m);
    float inv = 1.0f / (e0 + e1 + e2 + e3);
    at[b*4] = e0*inv; at[b*4+1] = e1*inv; at[b*4+2] = e2*inv; at[b*4+3] = e3*inv;
    attn[b*4] = at[b*4]; attn[b*4+1] = at[b*4+1];
    attn[b*4+2] = at[b*4+2]; attn[b*4+3] = at[b*4+3];
  }
  __syncthreads();
  for (int i = t; i < 8192; i += 256) {
    int b = i >> 8, f = i & 255;
    biasagg[i] = at[b*4]*biases[f] + at[b*4+1]*biases[256+f]
               + at[b*4+2]*biases[512+f] + at[b*4+3]*biases[768+f];
  }
}

// ---------------- kernel 3: weight aggregation + transpose to [b][tap][f][c] ----------------
__global__ __launch_bounds__(256)
void wagg_kernel(const float* __restrict__ kers, const float* __restrict__ attn,
                 bf16_t* __restrict__ wagg) {
  const int lid = blockIdx.x;     // 0..575
  const int xcd = lid & 7;
  const int sl  = lid >> 3;       // 0..71
  const int c8  = sl & 7;         // 32-channel chunk: c0 = c8*32
  const int tap = sl >> 3;        // 0..8
  const int b0  = xcd << 2;
  const int t   = threadIdx.x;
  __shared__ bf16_t tile[4][32 * 260];

  float a[4][4];
#pragma unroll
  for (int i = 0; i < 4; ++i)
#pragma unroll
    for (int k = 0; k < 4; ++k) a[i][k] = attn[(b0 + i) * 4 + k];

  const float* k0 = kers + ((size_t)(0 * 9 + tap)) * 65536 + (size_t)(c8 * 32) * 256;
  const float* k1 = kers + ((size_t)(1 * 9 + tap)) * 65536 + (size_t)(c8 * 32) * 256;
  const float* k2 = kers + ((size_t)(2 * 9 + tap)) * 65536 + (size_t)(c8 * 32) * 256;
  const float* k3 = kers + ((size_t)(3 * 9 + tap)) * 65536 + (size_t)(c8 * 32) * 256;

  const int fq = t & 63;       // f group: f0 = fq*4
  const int cl = t >> 6;       // 0..3
  const int f0 = fq * 4;
#pragma unroll
  for (int pass = 0; pass < 8; ++pass) {
    const int c_local = pass * 4 + cl;           // 0..31
    const size_t o = (size_t)c_local * 256 + f0;
    floatx4 v0 = *(const floatx4*)(k0 + o);
    floatx4 v1 = *(const floatx4*)(k1 + o);
    floatx4 v2 = *(const floatx4*)(k2 + o);
    floatx4 v3 = *(const floatx4*)(k3 + o);
#pragma unroll
    for (int i = 0; i < 4; ++i) {
      bf16x4 r;
#pragma unroll
      for (int j = 0; j < 4; ++j)
        r[j] = (bf16_t)(a[i][0] * v0[j] + a[i][1] * v1[j] + a[i][2] * v2[j] + a[i][3] * v3[j]);
      *(bf16x4*)&tile[i][c_local * 260 + f0] = r;   // 8B write, 8-aligned
    }
  }
  __syncthreads();

#pragma unroll
  for (int i = 0; i < 4; ++i) {
    bf16_t* wt = wagg + ((size_t)((b0 + i) * 9 + tap)) * 65536 + c8 * 32;
#pragma unroll
    for (int pass = 0; pass < 4; ++pass) {
      const int gi = pass * 256 + t;               // 0..1023
      const int f  = gi >> 2;                      // 0..255
      const int cg = gi & 3;                       // 0..3  (8-c granule within chunk)
      bf16x8 v;
#pragma unroll
      for (int jj = 0; jj < 8; ++jj) v[jj] = tile[i][(cg * 8 + jj) * 260 + f];
      *(bf16x8*)(wt + (size_t)f * 256 + cg * 8) = v;  // 16B store, 16-aligned
    }
  }
}

// ---------------- kernel 4: implicit-GEMM conv with per-sample weights ----------------
// v5: 512-thread block (8 waves = 2 m-groups x 4 f-slices), M=224 (8h x 28w), 448
// blocks, 1 block/CU. Full tap (ks0+ks1, 56 MFMA/wave) per barrier period: B staged
// as 32KB pair-tiles, triple-buffered, counted vmcnt(4). A-fragment register
// prefetch across taps (ks1 = aoff^64, next-tap load under ks1's MFMA shadow).
#define PBUF_BYTES 40960   // 320 pos (10 rows x 32 cols) * 128B
#define BBUF_BYTES 32768   // 256 f * 128B (full cq pair)

__global__ __launch_bounds__(512, 2)
void conv_mfma(const bf16_t* __restrict__ xpad, const bf16_t* __restrict__ wagg,
               const float* __restrict__ biasagg, float* __restrict__ out) {
  __shared__ char lds[PBUF_BYTES + 3 * BBUF_BYTES];  // 139264 B -> 1 block/CU
  char* ldsP = lds;
  char* ldsB = lds + PBUF_BYTES;

  // XCD swizzle: 448 blocks, 448 % 8 == 0 -> bijective; XCD x owns b = 4x..4x+3
  const int lid  = blockIdx.y * 14 + blockIdx.x;
  const int nid  = (lid & 7) * 56 + (lid >> 3);
  const int b    = nid / 14;
  const int tile = nid - b * 14;
  const int h0 = (tile >> 1) * 8;
  const int w0 = (tile & 1) * 28;

  const int tid  = threadIdx.x;
  const int lane = tid & 63;
  const int wv   = tid >> 6;     // 0..7
  const int mg   = wv >> 2;      // m-group (0: rows 0..111, 1: rows 112..223)
  const int fs   = wv & 3;       // f-slice
  const int l15  = lane & 15;
  const int quad = lane >> 4;
  const int n0   = fs * 64;

  const char* xb = (const char*)xpad + (size_t)b * (HP * WP * 256 * 2);
  const char* wb = (const char*)wagg + (size_t)b * (9 * 256 * 256 * 2);

  // static per-lane offsets
  int offs[7];
#pragma unroll
  for (int mi = 0; mi < 7; ++mi) {
    int m = mg * 112 + mi * 16 + l15;
    int ty = m / 28;
    int tx = m - ty * 28;
    offs[mi] = ty * 32 + tx;   // patch position index (32-col stride)
  }
  int boff[4];
#pragma unroll
  for (int ni = 0; ni < 4; ++ni) {
    int f = n0 + ni * 16 + l15;
    boff[ni] = f * 128 + ((quad ^ (f & 7)) << 4);  // ks0 granule; ks1 = ^64
  }
  // loop-invariant staging offsets
  int sb_off[4];
#pragma unroll
  for (int ii = 0; ii < 4; ++ii) {
    int i32 = wv * 4 + ii;
    int f = i32 * 8 + (lane >> 3);
    int gsrc = (lane & 7) ^ (f & 7);
    sb_off[ii] = f * 512 + gsrc * 16;
  }
  int sp_off[5];
#pragma unroll
  for (int ii = 0; ii < 5; ++ii) {
    int i40 = wv * 5 + ii;
    int p = i40 * 8 + (lane >> 3);       // 0..319
    int row = p >> 5, col = p & 31;
    int gsrc = (lane & 7) ^ (p & 7);
    sp_off[ii] = ((h0 + row) * WP + (w0 + col)) * 512 + gsrc * 16;
  }

  floatx4 acc[7][4];
#pragma unroll
  for (int mi = 0; mi < 7; ++mi)
#pragma unroll
    for (int ni = 0; ni < 4; ++ni) acc[mi][ni] = (floatx4){0.f, 0.f, 0.f, 0.f};

  auto stage_patch = [&](int cq) {
#pragma unroll
    for (int ii = 0; ii < 5; ++ii)
      async_copy16(xb + cq * 128 + sp_off[ii], ldsP + (wv * 5 + ii) * 1024);
  };
  auto stage_b = [&](int tap, int cq, int slot) {
    const char* wtb = wb + (size_t)tap * 131072 + cq * 128;
#pragma unroll
    for (int ii = 0; ii < 4; ++ii)
      async_copy16(wtb + sb_off[ii], ldsB + slot * BBUF_BYTES + (wv * 4 + ii) * 1024);
  };

  stage_patch(0);
  stage_b(0, 0, 0);

  bf16x8 aA[7], aB[7];
  int aoff[7];
  int slot = 0;

#pragma unroll 1
  for (int d = 0; d < 36; ++d) {
    const int cq  = d / 9;
    const int tap = d - cq * 9;
    const int s1 = (slot == 2) ? 0 : slot + 1;
    const bool last = (d == 35);

    if (!last) {
      const int nt = (tap == 8) ? 0 : tap + 1;
      const int nc = (tap == 8) ? cq + 1 : cq;
      stage_b(nt, nc, s1);
      // wait for everything except the 4 loads just issued (previous B pair and,
      // after a cq transition, the 5 patch loads, are older in the FIFO).
      asm volatile("s_waitcnt vmcnt(4)" ::: "memory");
    } else {
      asm volatile("s_waitcnt vmcnt(0)" ::: "memory");
    }
    __builtin_amdgcn_s_barrier();
    __builtin_amdgcn_sched_barrier(0);

    const char* bc = ldsB + slot * BBUF_BYTES;
    bf16x8 bv0 = *(const bf16x8*)(bc + boff[0]);
    bf16x8 bv1 = *(const bf16x8*)(bc + boff[1]);
    bf16x8 bv2 = *(const bf16x8*)(bc + boff[2]);
    bf16x8 bv3 = *(const bf16x8*)(bc + boff[3]);
    if (tap == 0) {
      // fresh patch (or first iter): load current tap's ks0 fragments inline
#pragma unroll
      for (int mi = 0; mi < 7; ++mi) {
        int p = offs[mi];                 // tapoff(0) == 0
        aoff[mi] = (p << 7) + ((quad ^ (p & 7)) << 4);
        aA[mi] = *(const bf16x8*)(ldsP + aoff[mi]);
      }
    }
    __builtin_amdgcn_s_setprio(1);
#pragma unroll
    for (int mi = 0; mi < 7; ++mi) {
      acc[mi][0] = __builtin_amdgcn_mfma_f32_16x16x32_bf16(aA[mi], bv0, acc[mi][0], 0, 0, 0);
      acc[mi][1] = __builtin_amdgcn_mfma_f32_16x16x32_bf16(aA[mi], bv1, acc[mi][1], 0, 0, 0);
      acc[mi][2] = __builtin_amdgcn_mfma_f32_16x16x32_bf16(aA[mi], bv2, acc[mi][2], 0, 0, 0);
      acc[mi][3] = __builtin_amdgcn_mfma_f32_16x16x32_bf16(aA[mi], bv3, acc[mi][3], 0, 0, 0);
    }
    __builtin_amdgcn_s_setprio(0);

    // mid region: ks1 operands + next tap's ks0 A-fragments (patch is stable)
    bf16x8 cv0 = *(const bf16x8*)(bc + (boff[0] ^ 64));
    bf16x8 cv1 = *(const bf16x8*)(bc + (boff[1] ^ 64));
    bf16x8 cv2 = *(const bf16x8*)(bc + (boff[2] ^ 64));
    bf16x8 cv3 = *(const bf16x8*)(bc + (boff[3] ^ 64));
#pragma unroll
    for (int mi = 0; mi < 7; ++mi)
      aB[mi] = *(const bf16x8*)(ldsP + (aoff[mi] ^ 64));
    if (tap < 8) {
      const int ntapoff = ((tap + 1) / 3) * 32 + ((tap + 1) % 3);
#pragma unroll
      for (int mi = 0; mi < 7; ++mi) {
        int p = offs[mi] + ntapoff;
        aoff[mi] = (p << 7) + ((quad ^ (p & 7)) << 4);
        aA[mi] = *(const bf16x8*)(ldsP + aoff[mi]);
      }
    }
    __builtin_amdgcn_s_setprio(1);
#pragma unroll
    for (int mi = 0; mi < 7; ++mi) {
      acc[mi][0] = __builtin_amdgcn_mfma_f32_16x16x32_bf16(aB[mi], cv0, acc[mi][0], 0, 0, 0);
      acc[mi][1] = __builtin_amdgcn_mfma_f32_16x16x32_bf16(aB[mi], cv1, acc[mi][1], 0, 0, 0);
      acc[mi][2] = __builtin_amdgcn_mfma_f32_16x16x32_bf16(aB[mi], cv2, acc[mi][2], 0, 0, 0);
      acc[mi][3] = __builtin_amdgcn_mfma_f32_16x16x32_bf16(aB[mi], cv3, acc[mi][3], 0, 0, 0);
    }
    __builtin_amdgcn_s_setprio(0);

    if (tap == 8 && cq < 3) {
      // all waves done reading the old patch (A-reads complete before their MFMAs)
      __builtin_amdgcn_s_barrier();
      stage_patch(cq + 1);   // 5 loads: older than next step's B stage -> covered
    }
    slot = s1;
  }

  // epilogue: D layout col=lane&15 (f), row=quad*4+reg (m)
  float bias[4];
#pragma unroll
  for (int ni = 0; ni < 4; ++ni) bias[ni] = biasagg[b * 256 + n0 + ni * 16 + l15];
  float* outb = out + (size_t)b * (56 * 56 * 256);
#pragma unroll
  for (int mi = 0; mi < 7; ++mi) {
#pragma unroll
    for (int rg = 0; rg < 4; ++rg) {
      int m = mg * 112 + mi * 16 + quad * 4 + rg;
      int ty = m / 28, tx = m - ty * 28;
      float* orow = outb + ((size_t)((h0 + ty) * 56) + (w0 + tx)) * 256 + n0 + l15;
#pragma unroll
      for (int ni = 0; ni < 4; ++ni) orow[ni * 16] = acc[mi][ni][rg] + bias[ni];
    }
  }
}

extern "C" void kernel_launch(void* const* d_in, const int* in_sizes, int n_in,
                              void* d_out, int out_size, void* d_ws, size_t ws_size,
                              hipStream_t stream) {
  const float* x      = (const float*)d_in[0];
  const float* kers   = (const float*)d_in[1];
  const float* biases = (const float*)d_in[2];
  const float* w1     = (const float*)d_in[3];
  const float* b1     = (const float*)d_in[4];
  const float* w2     = (const float*)d_in[5];
  const float* b2     = (const float*)d_in[6];
  float* outp = (float*)d_out;
  char* ws = (char*)d_ws;

  bf16_t* xpad   = (bf16_t*)(ws + XPAD_OFF);
  bf16_t* wagg   = (bf16_t*)(ws + WAGG_OFF);
  float* pooled  = (float*)(ws + POOLED_OFF);
  float* attn    = (float*)(ws + ATTN_OFF);
  float* biasagg = (float*)(ws + BIASAGG_OFF);

  hipMemsetAsync(pooled, 0, 32 * 256 * sizeof(float), stream);
  pad_pool<<<dim3(58, 32), 256, 0, stream>>>(x, xpad, pooled);
  router<<<1, 256, 0, stream>>>(pooled, w1, b1, w2, b2, biases, attn, biasagg);
  wagg_kernel<<<dim3(576), 256, 0, stream>>>(kers, attn, wagg);
  conv_mfma<<<dim3(14, 32), 512, 0, stream>>>(xpad, wagg, biasagg, outp);
}

// Round 5
// 357.029 us; speedup vs baseline: 1.0789x; 1.0133x over previous
//
#include <hip/hip_runtime.h>
#include <hip/hip_bf16.h>
#include <stdint.h>

typedef __bf16 bf16_t;
typedef __bf16 bf16x4 __attribute__((ext_vector_type(4)));
typedef __bf16 bf16x8 __attribute__((ext_vector_type(8)));
typedef float floatx4 __attribute__((ext_vector_type(4)));

#define B_ 32
#define HP 58
#define WP 66

// ws layout (bytes)
#define XPAD_OFF   0u
#define WAGG_OFF   62717952u     // 32*58*66*256*2
#define POOLED_OFF 100466688u    // + 32*9*256*256*2
#define ATTN_OFF   100499456u
#define BIASAGG_OFF 100499968u

__device__ __forceinline__ void async_copy16(const void* gsrc, void* ldst) {
  __builtin_amdgcn_global_load_lds(
      (const __attribute__((address_space(1))) unsigned int*)gsrc,
      (__attribute__((address_space(3))) unsigned int*)ldst, 16, 0, 0);
}

// ---------------- kernel 1: pad + convert + GAP partial sums ----------------
__global__ __launch_bounds__(256)
void pad_pool(const float* __restrict__ x, bf16_t* __restrict__ xpad,
              float* __restrict__ pooled) {
  const int hp = blockIdx.x;   // 0..57
  const int b  = blockIdx.y;
  const int t  = threadIdx.x;
  const int c4 = (t & 63) << 2;   // 0..252 (float4 channel group)
  const int wq = t >> 6;          // 0..3
  const int h  = hp - 1;
  const bool hvalid = (h >= 0) && (h < 56);
  bf16_t* dst = xpad + ((size_t)(b * 58 + hp)) * (66 * 256);
  const float* srcrow = x + ((size_t)(b * 56 + (hvalid ? h : 0))) * (56 * 256);
  floatx4 sum = {0.f, 0.f, 0.f, 0.f};
  for (int wp = wq; wp < 66; wp += 4) {
    const int w = wp - 1;
    floatx4 v = {0.f, 0.f, 0.f, 0.f};
    if (hvalid && (unsigned)w < 56u) {
      v = *(const floatx4*)(srcrow + w * 256 + c4);
      sum += v;
    }
    bf16x4 r;
#pragma unroll
    for (int j = 0; j < 4; ++j) r[j] = (bf16_t)v[j];
    *(bf16x4*)(dst + wp * 256 + c4) = r;
  }
  __shared__ floatx4 red[4][64];
  red[wq][t & 63] = sum;
  __syncthreads();
  if (hvalid && t < 64) {
    floatx4 s = red[0][t] + red[1][t] + red[2][t] + red[3][t];
#pragma unroll
    for (int j = 0; j < 4; ++j) atomicAdd(&pooled[b * 256 + t * 4 + j], s[j]);
  }
}

// ---------------- kernel 2: router MLP + softmax + bias agg ----------------
__global__ __launch_bounds__(256)
void router(const float* __restrict__ pooled, const float* __restrict__ w1,
            const float* __restrict__ b1, const float* __restrict__ w2,
            const float* __restrict__ b2, const float* __restrict__ biases,
            float* __restrict__ attn, float* __restrict__ biasagg) {
  __shared__ float ps[8192];
  __shared__ float w1s[16384];
  __shared__ float hs[2048];
  __shared__ float lg[128];
  __shared__ float at[128];
  const int t = threadIdx.x;
  for (int i = t; i < 8192; i += 256) ps[i] = pooled[i] * (1.0f / 3136.0f);
  for (int i = t; i < 4096; i += 256)
    *(floatx4*)&w1s[i * 4] = *(const floatx4*)&w1[i * 4];
  __syncthreads();
  for (int task = t; task < 2048; task += 256) {
    const int b = task >> 6, j = task & 63;
    const float* pb = ps + b * 256;
    float s0 = 0.f, s1 = 0.f, s2 = 0.f, s3 = 0.f;
#pragma unroll 4
    for (int c = 0; c < 256; c += 4) {
      s0 += pb[c]     * w1s[c * 64 + j];
      s1 += pb[c + 1] * w1s[(c + 1) * 64 + j];
      s2 += pb[c + 2] * w1s[(c + 2) * 64 + j];
      s3 += pb[c + 3] * w1s[(c + 3) * 64 + j];
    }
    hs[task] = fmaxf((s0 + s1) + (s2 + s3) + b1[j], 0.f);
  }
  __syncthreads();
  if (t < 128) {
    int b = t >> 2, k = t & 3;
    float s = b2[k];
    const float* hb = hs + b * 64;
#pragma unroll 4
    for (int j = 0; j < 64; ++j) s += hb[j] * w2[j * 4 + k];
    lg[t] = s * (1.0f / 30.0f);
  }
  __syncthreads();
  if (t < 32) {
    int b = t;
    float z0 = lg[b*4], z1 = lg[b*4+1], z2 = lg[b*4+2], z3 = lg[b*4+3];
    float m = fmaxf(fmaxf(z0, z1), fmaxf(z2, z3));
    float e0 = expf(z0-m), e1 = expf(z1-m), e2 = expf(z2-m), e3 = expf(z3-m);
    float inv = 1.0f / (e0 + e1 + e2 + e3);
    at[b*4] = e0*inv; at[b*4+1] = e1*inv; at[b*4+2] = e2*inv; at[b*4+3] = e3*inv;
    attn[b*4] = at[b*4]; attn[b*4+1] = at[b*4+1];
    attn[b*4+2] = at[b*4+2]; attn[b*4+3] = at[b*4+3];
  }
  __syncthreads();
  for (int i = t; i < 8192; i += 256) {
    int b = i >> 8, f = i & 255;
    biasagg[i] = at[b*4]*biases[f] + at[b*4+1]*biases[256+f]
               + at[b*4+2]*biases[512+f] + at[b*4+3]*biases[768+f];
  }
}

// ---------------- kernel 3: weight aggregation + transpose to [b][tap][f][c] ----------------
__global__ __launch_bounds__(256)
void wagg_kernel(const float* __restrict__ kers, const float* __restrict__ attn,
                 bf16_t* __restrict__ wagg) {
  const int lid = blockIdx.x;     // 0..575
  const int xcd = lid & 7;
  const int sl  = lid >> 3;       // 0..71
  const int c8  = sl & 7;         // 32-channel chunk: c0 = c8*32
  const int tap = sl >> 3;        // 0..8
  const int b0  = xcd << 2;
  const int t   = threadIdx.x;
  __shared__ bf16_t tile[4][32 * 260];

  float a[4][4];
#pragma unroll
  for (int i = 0; i < 4; ++i)
#pragma unroll
    for (int k = 0; k < 4; ++k) a[i][k] = attn[(b0 + i) * 4 + k];

  const float* k0 = kers + ((size_t)(0 * 9 + tap)) * 65536 + (size_t)(c8 * 32) * 256;
  const float* k1 = kers + ((size_t)(1 * 9 + tap)) * 65536 + (size_t)(c8 * 32) * 256;
  const float* k2 = kers + ((size_t)(2 * 9 + tap)) * 65536 + (size_t)(c8 * 32) * 256;
  const float* k3 = kers + ((size_t)(3 * 9 + tap)) * 65536 + (size_t)(c8 * 32) * 256;

  const int fq = t & 63;       // f group: f0 = fq*4
  const int cl = t >> 6;       // 0..3
  const int f0 = fq * 4;
#pragma unroll
  for (int pass = 0; pass < 8; ++pass) {
    const int c_local = pass * 4 + cl;           // 0..31
    const size_t o = (size_t)c_local * 256 + f0;
    floatx4 v0 = *(const floatx4*)(k0 + o);
    floatx4 v1 = *(const floatx4*)(k1 + o);
    floatx4 v2 = *(const floatx4*)(k2 + o);
    floatx4 v3 = *(const floatx4*)(k3 + o);
#pragma unroll
    for (int i = 0; i < 4; ++i) {
      bf16x4 r;
#pragma unroll
      for (int j = 0; j < 4; ++j)
        r[j] = (bf16_t)(a[i][0] * v0[j] + a[i][1] * v1[j] + a[i][2] * v2[j] + a[i][3] * v3[j]);
      *(bf16x4*)&tile[i][c_local * 260 + f0] = r;   // 8B write, 8-aligned
    }
  }
  __syncthreads();

#pragma unroll
  for (int i = 0; i < 4; ++i) {
    bf16_t* wt = wagg + ((size_t)((b0 + i) * 9 + tap)) * 65536 + c8 * 32;
#pragma unroll
    for (int pass = 0; pass < 4; ++pass) {
      const int gi = pass * 256 + t;               // 0..1023
      const int f  = gi >> 2;                      // 0..255
      const int cg = gi & 3;                       // 0..3  (8-c granule within chunk)
      bf16x8 v;
#pragma unroll
      for (int jj = 0; jj < 8; ++jj) v[jj] = tile[i][(cg * 8 + jj) * 260 + f];
      *(bf16x8*)(wt + (size_t)f * 256 + cg * 8) = v;  // 16B store, 16-aligned
    }
  }
}

// ---------------- kernel 4: implicit-GEMM conv with per-sample weights ----------------
// v7: race-free read-ahead. Visibility protocol: data staged by global_load_lds is
// readable only after (every wave drained its OWN loads via vmcnt(0)) -> barrier.
// Per period d: [barrier; stage B(d+1); read bv/cv (tile d) + aB (patch); MFMA ks0;
// pre-read aA' for d+1 from patch (stable; staged a full cq ahead); stage patch at
// tap0; MFMA ks1; vmcnt(0)]. Only 4 ds_reads (bv) exposed post-barrier; cv/aB/aA'
// hide under MFMA clusters. B double-buffered, patch double-buffered.
#define PBUF_BYTES 40960   // 320 pos (10 rows x 32 cols) * 128B
#define BBUF_BYTES 32768   // 256 f * 128B (full cq pair)

__global__ __launch_bounds__(512, 2)
void conv_mfma(const bf16_t* __restrict__ xpad, const bf16_t* __restrict__ wagg,
               const float* __restrict__ biasagg, float* __restrict__ out) {
  __shared__ char lds[2 * PBUF_BYTES + 2 * BBUF_BYTES];  // 147456 B
  char* ldsP0 = lds;
  char* ldsP1 = lds + PBUF_BYTES;
  char* ldsB  = lds + 2 * PBUF_BYTES;

  // XCD swizzle: 448 blocks, 448 % 8 == 0 -> bijective; XCD x owns b = 4x..4x+3
  const int lid  = blockIdx.y * 14 + blockIdx.x;
  const int nid  = (lid & 7) * 56 + (lid >> 3);
  const int b    = nid / 14;
  const int tile = nid - b * 14;
  const int h0 = (tile >> 1) * 8;
  const int w0 = (tile & 1) * 28;

  const int tid  = threadIdx.x;
  const int lane = tid & 63;
  const int wv   = tid >> 6;     // 0..7
  const int mg   = wv >> 2;      // m-group (0: rows 0..111, 1: rows 112..223)
  const int fs   = wv & 3;       // f-slice
  const int l15  = lane & 15;
  const int quad = lane >> 4;
  const int n0   = fs * 64;

  const char* xb = (const char*)xpad + (size_t)b * (HP * WP * 256 * 2);
  const char* wb = (const char*)wagg + (size_t)b * (9 * 256 * 256 * 2);

  // static per-lane offsets
  int offs[7];
#pragma unroll
  for (int mi = 0; mi < 7; ++mi) {
    int m = mg * 112 + mi * 16 + l15;
    int ty = m / 28;
    int tx = m - ty * 28;
    offs[mi] = ty * 32 + tx;   // patch position index (32-col stride)
  }
  int boff[4];
#pragma unroll
  for (int ni = 0; ni < 4; ++ni) {
    int f = n0 + ni * 16 + l15;
    boff[ni] = f * 128 + ((quad ^ (f & 7)) << 4);  // ks0 granule; ks1 = ^64
  }
  // loop-invariant staging offsets
  int sb_off[4];
#pragma unroll
  for (int ii = 0; ii < 4; ++ii) {
    int i32 = wv * 4 + ii;
    int f = i32 * 8 + (lane >> 3);
    int gsrc = (lane & 7) ^ (f & 7);
    sb_off[ii] = f * 512 + gsrc * 16;
  }
  int sp_off[5];
#pragma unroll
  for (int ii = 0; ii < 5; ++ii) {
    int i40 = wv * 5 + ii;
    int p = i40 * 8 + (lane >> 3);       // 0..319
    int row = p >> 5, col = p & 31;
    int gsrc = (lane & 7) ^ (p & 7);
    sp_off[ii] = ((h0 + row) * WP + (w0 + col)) * 512 + gsrc * 16;
  }

  floatx4 acc[7][4];
#pragma unroll
  for (int mi = 0; mi < 7; ++mi)
#pragma unroll
    for (int ni = 0; ni < 4; ++ni) acc[mi][ni] = (floatx4){0.f, 0.f, 0.f, 0.f};

  auto stage_patch = [&](int cq, char* pdst) {
#pragma unroll
    for (int ii = 0; ii < 5; ++ii)
      async_copy16(xb + cq * 128 + sp_off[ii], pdst + (wv * 5 + ii) * 1024);
  };
  auto stage_b = [&](int tap, int cq, int slot) {
    const char* wtb = wb + (size_t)tap * 131072 + cq * 128;
#pragma unroll
    for (int ii = 0; ii < 4; ++ii)
      async_copy16(wtb + sb_off[ii], ldsB + slot * BBUF_BYTES + (wv * 4 + ii) * 1024);
  };

  // prologue: patch cq0 + B tile 0; own-drain + barrier => both fully visible
  stage_patch(0, ldsP0);
  stage_b(0, 0, 0);
  asm volatile("s_waitcnt vmcnt(0)" ::: "memory");
  __builtin_amdgcn_s_barrier();
  __builtin_amdgcn_sched_barrier(0);

  bf16x8 aA[7], aB[7];
  int aoff[7];
#pragma unroll
  for (int mi = 0; mi < 7; ++mi) {
    int p = offs[mi];                    // tapoff(0) == 0
    aoff[mi] = (p << 7) + ((quad ^ (p & 7)) << 4);
    aA[mi] = *(const bf16x8*)(ldsP0 + aoff[mi]);
  }

#pragma unroll 1
  for (int d = 0; d < 36; ++d) {
    const int cq  = d / 9;
    const int tap = d - cq * 9;
    const int cs  = cq & 1;
    char* pbc = cs ? ldsP1 : ldsP0;
    char* pbn = cs ? ldsP0 : ldsP1;
    const char* bc = ldsB + (d & 1) * BBUF_BYTES;
    const bool haveNext = (d < 35);

    // head barrier: tile d (staged at d-1, own-drained at end of d-1) is now
    // visible from ALL waves. (d=0: prologue staged+drained+barrier'd.)
    __builtin_amdgcn_s_barrier();
    __builtin_amdgcn_sched_barrier(0);

    // stage next B tile into the other slot (its old tile d-1 was last read
    // during period d-1, before this barrier -> WAR safe)
    if (haveNext) {
      const int nt = (tap == 8) ? 0 : tap + 1;
      const int nc = (tap == 8) ? cq + 1 : cq;
      stage_b(nt, nc, (d + 1) & 1);
    }

    // operand reads for THIS period: bv on critical path (4 reads), cv + aB
    // hide under the ks0 MFMA cluster (compiler's fine-grained lgkmcnt).
    bf16x8 bv0 = *(const bf16x8*)(bc + boff[0]);
    bf16x8 bv1 = *(const bf16x8*)(bc + boff[1]);
    bf16x8 bv2 = *(const bf16x8*)(bc + boff[2]);
    bf16x8 bv3 = *(const bf16x8*)(bc + boff[3]);
    bf16x8 cv0 = *(const bf16x8*)(bc + (boff[0] ^ 64));
    bf16x8 cv1 = *(const bf16x8*)(bc + (boff[1] ^ 64));
    bf16x8 cv2 = *(const bf16x8*)(bc + (boff[2] ^ 64));
    bf16x8 cv3 = *(const bf16x8*)(bc + (boff[3] ^ 64));
#pragma unroll
    for (int mi = 0; mi < 7; ++mi)
      aB[mi] = *(const bf16x8*)(pbc + (aoff[mi] ^ 64));

    __builtin_amdgcn_s_setprio(1);
#pragma unroll
    for (int mi = 0; mi < 7; ++mi) {
      acc[mi][0] = __builtin_amdgcn_mfma_f32_16x16x32_bf16(aA[mi], bv0, acc[mi][0], 0, 0, 0);
      acc[mi][1] = __builtin_amdgcn_mfma_f32_16x16x32_bf16(aA[mi], bv1, acc[mi][1], 0, 0, 0);
      acc[mi][2] = __builtin_amdgcn_mfma_f32_16x16x32_bf16(aA[mi], bv2, acc[mi][2], 0, 0, 0);
      acc[mi][3] = __builtin_amdgcn_mfma_f32_16x16x32_bf16(aA[mi], bv3, acc[mi][3], 0, 0, 0);
    }
    __builtin_amdgcn_s_setprio(0);

    if (haveNext) {
      // pre-read next period's ks0 A-fragments. Patch buffers are stable:
      // patch(cq+1) was staged at period 9cq (visible since 9cq+1); first
      // pre-read here is at period 9cq+8. WAR on pbn closed at the 9cq barrier.
      const char* npb = (tap == 8) ? pbn : pbc;
      const int ntapoff = (tap == 8) ? 0 : (((tap + 1) / 3) * 32 + ((tap + 1) % 3));
#pragma unroll
      for (int mi = 0; mi < 7; ++mi) {
        int p = offs[mi] + ntapoff;
        aoff[mi] = (p << 7) + ((quad ^ (p & 7)) << 4);
        aA[mi] = *(const bf16x8*)(npb + aoff[mi]);
      }
      if (tap == 0 && cq < 3) stage_patch(cq + 1, pbn);
    }

    __builtin_amdgcn_s_setprio(1);
#pragma unroll
    for (int mi = 0; mi < 7; ++mi) {
      acc[mi][0] = __builtin_amdgcn_mfma_f32_16x16x32_bf16(aB[mi], cv0, acc[mi][0], 0, 0, 0);
      acc[mi][1] = __builtin_amdgcn_mfma_f32_16x16x32_bf16(aB[mi], cv1, acc[mi][1], 0, 0, 0);
      acc[mi][2] = __builtin_amdgcn_mfma_f32_16x16x32_bf16(aB[mi], cv2, acc[mi][2], 0, 0, 0);
      acc[mi][3] = __builtin_amdgcn_mfma_f32_16x16x32_bf16(aB[mi], cv3, acc[mi][3], 0, 0, 0);
    }
    __builtin_amdgcn_s_setprio(0);

    // own-drain of this period's staging, BEFORE the next head barrier:
    // after that barrier, tile d+1 (and any patch staged here) is visible.
    if (haveNext) asm volatile("s_waitcnt vmcnt(0)" ::: "memory");
  }

  // epilogue: D layout col=lane&15 (f), row=quad*4+reg (m)
  float bias[4];
#pragma unroll
  for (int ni = 0; ni < 4; ++ni) bias[ni] = biasagg[b * 256 + n0 + ni * 16 + l15];
  float* outb = out + (size_t)b * (56 * 56 * 256);
#pragma unroll
  for (int mi = 0; mi < 7; ++mi) {
#pragma unroll
    for (int rg = 0; rg < 4; ++rg) {
      int m = mg * 112 + mi * 16 + quad * 4 + rg;
      int ty = m / 28, tx = m - ty * 28;
      float* orow = outb + ((size_t)((h0 + ty) * 56) + (w0 + tx)) * 256 + n0 + l15;
#pragma unroll
      for (int ni = 0; ni < 4; ++ni) orow[ni * 16] = acc[mi][ni][rg] + bias[ni];
    }
  }
}

extern "C" void kernel_launch(void* const* d_in, const int* in_sizes, int n_in,
                              void* d_out, int out_size, void* d_ws, size_t ws_size,
                              hipStream_t stream) {
  const float* x      = (const float*)d_in[0];
  const float* kers   = (const float*)d_in[1];
  const float* biases = (const float*)d_in[2];
  const float* w1     = (const float*)d_in[3];
  const float* b1     = (const float*)d_in[4];
  const float* w2     = (const float*)d_in[5];
  const float* b2     = (const float*)d_in[6];
  float* outp = (float*)d_out;
  char* ws = (char*)d_ws;

  bf16_t* xpad   = (bf16_t*)(ws + XPAD_OFF);
  bf16_t* wagg   = (bf16_t*)(ws + WAGG_OFF);
  float* pooled  = (float*)(ws + POOLED_OFF);
  float* attn    = (float*)(ws + ATTN_OFF);
  float* biasagg = (float*)(ws + BIASAGG_OFF);

  hipMemsetAsync(pooled, 0, 32 * 256 * sizeof(float), stream);
  pad_pool<<<dim3(58, 32), 256, 0, stream>>>(x, xpad, pooled);
  router<<<1, 256, 0, stream>>>(pooled, w1, b1, w2, b2, biases, attn, biasagg);
  wagg_kernel<<<dim3(576), 256, 0, stream>>>(kers, attn, wagg);
  conv_mfma<<<dim3(14, 32), 512, 0, stream>>>(xpad, wagg, biasagg, outp);
}